// Round 5
// baseline (61565.759 us; speedup 1.0000x reference)
//
#include <hip/hip_runtime.h>
#include <hip/hip_bf16.h>

#define T_STEPS 4096
#define HID 128
#define INP 8
#define MID 50
#define MIDP 52   // padded to multiple of 4
#define KSUB 10

typedef float v2f __attribute__((ext_vector_type(2)));

__device__ __forceinline__ v2f mk2(float a, float b){ v2f r; r.x = a; r.y = b; return r; }
__device__ __forceinline__ v2f bc2(float s){ v2f r; r.x = s; r.y = s; return r; }

__device__ __forceinline__ v2f fma2(v2f a, v2f b, v2f c){
#if __has_builtin(__builtin_elementwise_fma)
    return __builtin_elementwise_fma(a, b, c);
#else
    c.x = fmaf(a.x, b.x, c.x); c.y = fmaf(a.y, b.y, c.y); return c;
#endif
}

__device__ __forceinline__ float fast_tanh(float x){
    float e = __expf(2.0f * x);
    return 1.0f - 2.0f / (e + 1.0f);
}
__device__ __forceinline__ float softplus_f(float x){
    return (x > 20.0f) ? x : __logf(1.0f + __expf(x));
}

// lgkmcnt-only barrier: orders LDS ops, lets global loads stay in flight.
__device__ __forceinline__ void wg_barrier(){
    asm volatile("s_waitcnt lgkmcnt(0)\n\ts_barrier" ::: "memory");
}

// 3 waves:
//   wave0: ENTIRE recurrence (phase A + phase B), zero barriers in substep loop
//          (single-wave LDS coherence needs only lgkmcnt). Snapshots z once per
//          t-step into zsnap[t&1], then ONE barrier.
//   wave1: sigma head from zsnap.   wave2: mu head from zsnap.
__global__ __launch_bounds__(192, 1)
void lode_kernel(const float* __restrict__ x, const float* __restrict__ dt,
                 const float* __restrict__ W1, const float* __restrict__ b1,
                 const float* __restrict__ W2, const float* __restrict__ b2,
                 const float* __restrict__ Wls1, const float* __restrict__ bls1,
                 const float* __restrict__ wls2, const float* __restrict__ bls2,
                 const float* __restrict__ Wlm1, const float* __restrict__ blm1,
                 float* __restrict__ out)
{
    __shared__ __align__(16) float zsh[HID];        // working z (wave0-private)
    __shared__ __align__(16) float h1sh[64];        // mid activations (wave0-private)
    __shared__ __align__(16) float zsnap[2][HID];   // per-step z snapshot for heads

    const int tid = threadIdx.x;
    const int wid = tid >> 6;
    const int l   = tid & 63;

    if (wid == 0){
        // ================= wave 0: full recurrence =================
        const int lc = (l < MID) ? l : 0;          // clamp loads in-bounds
        // W1 z-part packed: w1[i] = (W1[2i][l], W1[2i+1][l])
        v2f w1[HID/2];
        #pragma unroll
        for (int i = 0; i < HID/2; ++i){
            const float a = W1[(2*i  )*MID + lc];
            const float b = W1[(2*i+1)*MID + lc];
            w1[i] = (l < MID) ? mk2(a, b) : mk2(0.0f, 0.0f);
        }
        float w1x[INP];
        #pragma unroll
        for (int j = 0; j < INP; ++j){
            const float v = W1[(HID+j)*MID + lc];
            w1x[j] = (l < MID) ? v : 0.0f;
        }
        const float b1c = (l < MID) ? b1[lc] : 0.0f;

        // W2 pair-columns: w2p[k] = (W2[k][2l], W2[k][2l+1])
        v2f w2p[MIDP];
        #pragma unroll
        for (int k = 0; k < MIDP; ++k){
            if (k < MID) w2p[k] = mk2(W2[k*HID + 2*l], W2[k*HID + 2*l+1]);
            else         w2p[k] = mk2(0.0f, 0.0f);
        }
        const v2f b2p = mk2(b2[2*l], b2[2*l+1]);

        v2f z2 = bc2(0.0f);
        *reinterpret_cast<v2f*>(&zsh[2*l]) = z2;   // z0 = 0 (same-wave, no barrier)

        // prefetch t=0 inputs
        float4 xa = *reinterpret_cast<const float4*>(&x[0]);
        float4 xb = *reinterpret_cast<const float4*>(&x[4]);
        float2 dtc = *reinterpret_cast<const float2*>(&dt[0]);

        for (int t = 0; t < T_STEPS; ++t){
            // issue next step's loads now; they stay in flight across the
            // whole substep loop (barrier is lgkm-only).
            const int tn = (t+1 < T_STEPS) ? t+1 : t;
            const float4 xan = *reinterpret_cast<const float4*>(&x[tn*INP]);
            const float4 xbn = *reinterpret_cast<const float4*>(&x[tn*INP+4]);
            const float2 dtn = *reinterpret_cast<const float2*>(&dt[2*tn]);

            float xacc = b1c;
            xacc = fmaf(xa.x, w1x[0], xacc); xacc = fmaf(xa.y, w1x[1], xacc);
            xacc = fmaf(xa.z, w1x[2], xacc); xacc = fmaf(xa.w, w1x[3], xacc);
            xacc = fmaf(xb.x, w1x[4], xacc); xacc = fmaf(xb.y, w1x[5], xacc);
            xacc = fmaf(xb.z, w1x[6], xacc); xacc = fmaf(xb.w, w1x[7], xacc);
            const float hstep = (dtc.y - dtc.x) * (1.0f / KSUB);

            for (int s = 0; s < KSUB; ++s){
                // ---- phase A: h1[l] = tanh(xacc + sum_k z[k]*W1[k][l]) ----
                v2f a0 = mk2(xacc, 0.0f), a1 = bc2(0.0f), a2 = bc2(0.0f), a3 = bc2(0.0f);
                #pragma unroll
                for (int m = 0; m < HID/16; ++m){
                    const float4 q0 = *reinterpret_cast<const float4*>(&zsh[16*m+ 0]);
                    const float4 q1 = *reinterpret_cast<const float4*>(&zsh[16*m+ 4]);
                    const float4 q2 = *reinterpret_cast<const float4*>(&zsh[16*m+ 8]);
                    const float4 q3 = *reinterpret_cast<const float4*>(&zsh[16*m+12]);
                    a0 = fma2(mk2(q0.x, q0.y), w1[8*m+0], a0);
                    a1 = fma2(mk2(q0.z, q0.w), w1[8*m+1], a1);
                    a2 = fma2(mk2(q1.x, q1.y), w1[8*m+2], a2);
                    a3 = fma2(mk2(q1.z, q1.w), w1[8*m+3], a3);
                    a0 = fma2(mk2(q2.x, q2.y), w1[8*m+4], a0);
                    a1 = fma2(mk2(q2.z, q2.w), w1[8*m+5], a1);
                    a2 = fma2(mk2(q3.x, q3.y), w1[8*m+6], a2);
                    a3 = fma2(mk2(q3.z, q3.w), w1[8*m+7], a3);
                }
                const v2f aa = (a0 + a1) + (a2 + a3);
                h1sh[l] = fast_tanh(aa.x + aa.y);   // lanes >= 50 write tanh(0)=0

                // ---- phase B: z += hstep * tanh(W2^T h1 + b2) ----
                // same-wave LDS RAW: compiler inserts lgkmcnt wait.
                v2f d0 = b2p, d1 = bc2(0.0f), d2 = bc2(0.0f), d3 = bc2(0.0f);
                #pragma unroll
                for (int q = 0; q < MIDP/4; ++q){
                    const float4 hq = *reinterpret_cast<const float4*>(&h1sh[4*q]);
                    d0 = fma2(bc2(hq.x), w2p[4*q+0], d0);
                    d1 = fma2(bc2(hq.y), w2p[4*q+1], d1);
                    d2 = fma2(bc2(hq.z), w2p[4*q+2], d2);
                    d3 = fma2(bc2(hq.w), w2p[4*q+3], d3);
                }
                const v2f dd = (d0 + d1) + (d2 + d3);
                z2.x += hstep * fast_tanh(dd.x);
                z2.y += hstep * fast_tanh(dd.y);
                *reinterpret_cast<v2f*>(&zsh[2*l]) = z2;
            }

            // snapshot for heads, then the step's single barrier
            *reinterpret_cast<v2f*>(&zsnap[t&1][2*l]) = z2;
            wg_barrier();

            xa = xan; xb = xbn; dtc = dtn;
        }
    } else {
        // ================= waves 1,2: heads =================
        const float* __restrict__ Wh = (wid == 1) ? Wls1 : Wlm1;
        const float* __restrict__ bh = (wid == 1) ? bls1 : blm1;
        const v2f   bhp   = mk2(bh[2*l], bh[2*l+1]);
        const v2f   wls2p = mk2(wls2[2*l], wls2[2*l+1]);
        const float bls2s = bls2[0];

        for (int t = 0; t < T_STEPS; ++t){
            wg_barrier();   // pairs with wave0's end-of-step barrier
            const float* zs = &zsnap[t&1][0];
            v2f p = bhp;
            #pragma unroll 4
            for (int k = 0; k < HID; k += 4){
                const float4 zv = *reinterpret_cast<const float4*>(&zs[k]);
                const v2f a0 = *reinterpret_cast<const v2f*>(&Wh[(k+0)*HID + 2*l]);
                const v2f a1 = *reinterpret_cast<const v2f*>(&Wh[(k+1)*HID + 2*l]);
                const v2f a2 = *reinterpret_cast<const v2f*>(&Wh[(k+2)*HID + 2*l]);
                const v2f a3 = *reinterpret_cast<const v2f*>(&Wh[(k+3)*HID + 2*l]);
                p = fma2(bc2(zv.x), a0, p);
                p = fma2(bc2(zv.y), a1, p);
                p = fma2(bc2(zv.z), a2, p);
                p = fma2(bc2(zv.w), a3, p);
            }
            p.x = fast_tanh(p.x); p.y = fast_tanh(p.y);
            float r = p.x*wls2p.x + p.y*wls2p.y;
            #pragma unroll
            for (int off = 1; off < 64; off <<= 1) r += __shfl_xor(r, off, 64);
            if (l == 0){
                if (wid == 1) out[T_STEPS + t] = softplus_f(r + bls2s);  // sigma
                else          out[t]           = r + bls2s;              // mu (reuses ls2)
            }
        }
    }
}

extern "C" void kernel_launch(void* const* d_in, const int* in_sizes, int n_in,
                              void* d_out, int out_size, void* d_ws, size_t ws_size,
                              hipStream_t stream)
{
    const float* x    = (const float*)d_in[0];
    const float* dt   = (const float*)d_in[1];
    const float* W1   = (const float*)d_in[2];
    const float* b1   = (const float*)d_in[3];
    const float* W2   = (const float*)d_in[4];
    const float* b2   = (const float*)d_in[5];
    const float* Wls1 = (const float*)d_in[6];
    const float* bls1 = (const float*)d_in[7];
    const float* wls2 = (const float*)d_in[8];
    const float* bls2 = (const float*)d_in[9];
    const float* Wlm1 = (const float*)d_in[10];
    const float* blm1 = (const float*)d_in[11];
    float* out = (float*)d_out;

    hipLaunchKernelGGL(lode_kernel, dim3(1), dim3(192), 0, stream,
                       x, dt, W1, b1, W2, b2, Wls1, bls1, wls2, bls2, Wlm1, blm1, out);
}

// Round 6
// 30730.472 us; speedup vs baseline: 2.0034x; 2.0034x over previous
//
#include <hip/hip_runtime.h>
#include <hip/hip_bf16.h>

#define T_STEPS 4096
#define HID 128
#define INP 8
#define MID 50
#define KSUB 10

typedef float v2f __attribute__((ext_vector_type(2)));

__device__ __forceinline__ v2f mk2(float a, float b){ v2f r; r.x = a; r.y = b; return r; }
__device__ __forceinline__ v2f bc2(float s){ v2f r; r.x = s; r.y = s; return r; }

__device__ __forceinline__ v2f fma2(v2f a, v2f b, v2f c){
#if __has_builtin(__builtin_elementwise_fma)
    return __builtin_elementwise_fma(a, b, c);
#else
    c.x = fmaf(a.x, b.x, c.x); c.y = fmaf(a.y, b.y, c.y); return c;
#endif
}

__device__ __forceinline__ float fast_tanh(float x){
    float e = __expf(2.0f * x);
    return 1.0f - 2.0f / (e + 1.0f);
}
__device__ __forceinline__ float softplus_f(float x){
    return (x > 20.0f) ? x : __logf(1.0f + __expf(x));
}

// lgkmcnt-only barrier: orders LDS ops, lets global loads stay in flight.
__device__ __forceinline__ void wg_barrier(){
    asm volatile("s_waitcnt lgkmcnt(0)\n\ts_barrier" ::: "memory");
}

// 2 waves, K-split recurrence — ONE barrier per substep:
//   phase A: wave w accumulates k in [w*64, w*64+64) of h1's dot (reads its OWN
//            z half, which it wrote itself in phase B — no cross-wave dep).
//            Cross-wave exchange of the 50+50 partial sums via pbuf (dbuf'd).
//   phase B: wave w computes z[w*64 + l] (1 output/lane) from a wave-PRIVATE
//            h1 broadcast buffer (same-wave RAW needs no barrier).
// Heads (sigma on wave0, mu on wave1) run concurrently once per t-step behind
// one extra barrier. 11 barriers/t-step total (R4 had 20).
__global__ __launch_bounds__(128, 1)
void lode_kernel(const float* __restrict__ x, const float* __restrict__ dt,
                 const float* __restrict__ W1, const float* __restrict__ b1,
                 const float* __restrict__ W2, const float* __restrict__ b2,
                 const float* __restrict__ Wls1, const float* __restrict__ bls1,
                 const float* __restrict__ wls2, const float* __restrict__ bls2,
                 const float* __restrict__ Wlm1, const float* __restrict__ blm1,
                 float* __restrict__ out)
{
    __shared__ __align__(16) float zsh[HID];         // z; half w owned by wave w
    __shared__ __align__(8)  float pbuf[2][64][2];   // [dbuf][lane][wave] partials
    __shared__ __align__(16) float h1own[2][64];     // per-wave h1 broadcast copy

    const int tid  = threadIdx.x;
    const int wid  = tid >> 6;
    const int l    = tid & 63;
    const int base = wid << 6;

    const int lc = (l < MID) ? l : 0;   // clamp loads in-bounds

    // W1 rows [base, base+64), column lc, packed over k-pairs: 32 v2f
    v2f w1h[32];
    #pragma unroll
    for (int i = 0; i < 32; ++i){
        const float a = W1[(base + 2*i    )*MID + lc];
        const float b = W1[(base + 2*i + 1)*MID + lc];
        w1h[i] = (l < MID) ? mk2(a, b) : bc2(0.0f);
    }
    // x-part rows + bias: counted once, by wave1 only
    float w1x[INP];
    #pragma unroll
    for (int jj = 0; jj < INP; ++jj){
        const float v = W1[(HID + jj)*MID + lc];
        w1x[jj] = (wid == 1 && l < MID) ? v : 0.0f;
    }
    const float b1c = (wid == 1 && l < MID) ? b1[lc] : 0.0f;

    // W2 column (base + l): 25 v2f over k-pairs
    const int jcol = base + l;
    v2f w2c[25];
    #pragma unroll
    for (int q = 0; q < 25; ++q)
        w2c[q] = mk2(W2[(2*q)*HID + jcol], W2[(2*q + 1)*HID + jcol]);
    const float b2c = b2[jcol];

    // head constants (sigma head on wave0, mu head on wave1; both reuse wls2/bls2)
    const float* __restrict__ Wh = (wid == 0) ? Wls1 : Wlm1;
    const float* __restrict__ bh = (wid == 0) ? bls1 : blm1;
    const v2f   bhp   = mk2(bh[2*l], bh[2*l+1]);
    const v2f   wls2p = mk2(wls2[2*l], wls2[2*l+1]);
    const float bls2s = bls2[0];

    float zj = 0.0f;
    zsh[base + l] = 0.0f;   // own half; same-wave RAW, no barrier needed

    // prefetch t=0 inputs
    float4 xa  = *reinterpret_cast<const float4*>(&x[0]);
    float4 xb  = *reinterpret_cast<const float4*>(&x[4]);
    float2 dtc = *reinterpret_cast<const float2*>(&dt[0]);

    for (int t = 0; t < T_STEPS; ++t){
        // issue next step's loads; they stay in flight (barriers are lgkm-only)
        const int tn = (t + 1 < T_STEPS) ? t + 1 : t;
        const float4 xan = *reinterpret_cast<const float4*>(&x[tn*INP]);
        const float4 xbn = *reinterpret_cast<const float4*>(&x[tn*INP + 4]);
        const float2 dtn = *reinterpret_cast<const float2*>(&dt[2*tn]);

        // x-part of phase-A dot (wave1 real, wave0 zeros) — once per t-step
        float xacc = b1c;
        xacc = fmaf(xa.x, w1x[0], xacc); xacc = fmaf(xa.y, w1x[1], xacc);
        xacc = fmaf(xa.z, w1x[2], xacc); xacc = fmaf(xa.w, w1x[3], xacc);
        xacc = fmaf(xb.x, w1x[4], xacc); xacc = fmaf(xb.y, w1x[5], xacc);
        xacc = fmaf(xb.z, w1x[6], xacc); xacc = fmaf(xb.w, w1x[7], xacc);
        const float hstep = (dtc.y - dtc.x) * (1.0f / KSUB);

        #pragma unroll 2
        for (int s = 0; s < KSUB; ++s){
            // ---- phase A (K-split): partial_l = sum_{k in own half} z[k]*W1[k][l] ----
            v2f a0 = mk2(xacc, 0.0f), a1 = bc2(0.0f), a2 = bc2(0.0f), a3 = bc2(0.0f);
            #pragma unroll
            for (int m = 0; m < 4; ++m){
                const float4 q0 = *reinterpret_cast<const float4*>(&zsh[base + 16*m +  0]);
                const float4 q1 = *reinterpret_cast<const float4*>(&zsh[base + 16*m +  4]);
                const float4 q2 = *reinterpret_cast<const float4*>(&zsh[base + 16*m +  8]);
                const float4 q3 = *reinterpret_cast<const float4*>(&zsh[base + 16*m + 12]);
                a0 = fma2(mk2(q0.x, q0.y), w1h[8*m+0], a0);
                a1 = fma2(mk2(q0.z, q0.w), w1h[8*m+1], a1);
                a2 = fma2(mk2(q1.x, q1.y), w1h[8*m+2], a2);
                a3 = fma2(mk2(q1.z, q1.w), w1h[8*m+3], a3);
                a0 = fma2(mk2(q2.x, q2.y), w1h[8*m+4], a0);
                a1 = fma2(mk2(q2.z, q2.w), w1h[8*m+5], a1);
                a2 = fma2(mk2(q3.x, q3.y), w1h[8*m+6], a2);
                a3 = fma2(mk2(q3.z, q3.w), w1h[8*m+7], a3);
            }
            const v2f aa = (a0 + a1) + (a2 + a3);
            pbuf[s & 1][l][wid] = aa.x + aa.y;
            wg_barrier();                       // the substep's ONE barrier

            // ---- combine partials, broadcast h1 via wave-private buffer ----
            const float2 pp = *reinterpret_cast<const float2*>(&pbuf[s & 1][l][0]);
            h1own[wid][l] = fast_tanh(pp.x + pp.y);   // lanes >= 50 produce 0

            // ---- phase B: z[jcol] += hstep * tanh(b2 + sum_k h1[k]*W2[k][jcol]) ----
            v2f d0 = bc2(0.0f), d1 = bc2(0.0f), d2 = bc2(0.0f), d3 = bc2(0.0f);
            #pragma unroll
            for (int q2 = 0; q2 < 12; q2 += 4){
                const float4 h0 = *reinterpret_cast<const float4*>(&h1own[wid][4*q2 +  0]);
                const float4 h1v= *reinterpret_cast<const float4*>(&h1own[wid][4*q2 +  4]);
                const float4 h2 = *reinterpret_cast<const float4*>(&h1own[wid][4*q2 +  8]);
                const float4 h3 = *reinterpret_cast<const float4*>(&h1own[wid][4*q2 + 12]);
                d0 = fma2(mk2(h0.x, h0.y), w2c[2*q2+0], d0);
                d1 = fma2(mk2(h0.z, h0.w), w2c[2*q2+1], d1);
                d2 = fma2(mk2(h1v.x,h1v.y), w2c[2*q2+2], d2);
                d3 = fma2(mk2(h1v.z,h1v.w), w2c[2*q2+3], d3);
                d0 = fma2(mk2(h2.x, h2.y), w2c[2*q2+4], d0);
                d1 = fma2(mk2(h2.z, h2.w), w2c[2*q2+5], d1);
                d2 = fma2(mk2(h3.x, h3.y), w2c[2*q2+6], d2);
                d3 = fma2(mk2(h3.z, h3.w), w2c[2*q2+7], d3);
            }
            const float2 ht = *reinterpret_cast<const float2*>(&h1own[wid][48]);
            d0 = fma2(mk2(ht.x, ht.y), w2c[24], d0);
            const v2f dd = (d0 + d1) + (d2 + d3);
            zj += hstep * fast_tanh(b2c + dd.x + dd.y);
            zsh[base + l] = zj;                 // own half; next phase A reads it
        }

        wg_barrier();   // publish both z halves for the heads

        // ---- heads: sigma (wave0) and mu (wave1), concurrent ----
        v2f p = bhp;
        #pragma unroll 4
        for (int k = 0; k < HID; k += 4){
            const float4 zv = *reinterpret_cast<const float4*>(&zsh[k]);
            const v2f a0 = *reinterpret_cast<const v2f*>(&Wh[(k+0)*HID + 2*l]);
            const v2f a1 = *reinterpret_cast<const v2f*>(&Wh[(k+1)*HID + 2*l]);
            const v2f a2 = *reinterpret_cast<const v2f*>(&Wh[(k+2)*HID + 2*l]);
            const v2f a3 = *reinterpret_cast<const v2f*>(&Wh[(k+3)*HID + 2*l]);
            p = fma2(bc2(zv.x), a0, p);
            p = fma2(bc2(zv.y), a1, p);
            p = fma2(bc2(zv.z), a2, p);
            p = fma2(bc2(zv.w), a3, p);
        }
        p.x = fast_tanh(p.x); p.y = fast_tanh(p.y);
        float r = p.x*wls2p.x + p.y*wls2p.y;
        #pragma unroll
        for (int off = 1; off < 64; off <<= 1) r += __shfl_xor(r, off, 64);
        if (l == 0){
            if (wid == 0) out[T_STEPS + t] = softplus_f(r + bls2s);  // sigma
            else          out[t]           = r + bls2s;              // mu (reuses ls2)
        }

        xa = xan; xb = xbn; dtc = dtn;
    }
}

extern "C" void kernel_launch(void* const* d_in, const int* in_sizes, int n_in,
                              void* d_out, int out_size, void* d_ws, size_t ws_size,
                              hipStream_t stream)
{
    const float* x    = (const float*)d_in[0];
    const float* dt   = (const float*)d_in[1];
    const float* W1   = (const float*)d_in[2];
    const float* b1   = (const float*)d_in[3];
    const float* W2   = (const float*)d_in[4];
    const float* b2   = (const float*)d_in[5];
    const float* Wls1 = (const float*)d_in[6];
    const float* bls1 = (const float*)d_in[7];
    const float* wls2 = (const float*)d_in[8];
    const float* bls2 = (const float*)d_in[9];
    const float* Wlm1 = (const float*)d_in[10];
    const float* blm1 = (const float*)d_in[11];
    float* out = (float*)d_out;

    hipLaunchKernelGGL(lode_kernel, dim3(1), dim3(128), 0, stream,
                       x, dt, W1, b1, W2, b2, Wls1, bls1, wls2, bls2, Wlm1, blm1, out);
}

// Round 8
// 27484.344 us; speedup vs baseline: 2.2400x; 1.1181x over previous
//
#include <hip/hip_runtime.h>
#include <hip/hip_bf16.h>

#define T_STEPS 4096
#define HID 128
#define INP 8
#define MID 50
#define KSUB 10

typedef float v2f __attribute__((ext_vector_type(2)));

__device__ __forceinline__ v2f mk2(float a, float b){ v2f r; r.x = a; r.y = b; return r; }
__device__ __forceinline__ v2f bc2(float s){ v2f r; r.x = s; r.y = s; return r; }

__device__ __forceinline__ v2f fma2(v2f a, v2f b, v2f c){
#if __has_builtin(__builtin_elementwise_fma)
    return __builtin_elementwise_fma(a, b, c);
#else
    c.x = fmaf(a.x, b.x, c.x); c.y = fmaf(a.y, b.y, c.y); return c;
#endif
}

__device__ __forceinline__ float fast_tanh(float x){
    float e = __expf(2.0f * x);
    return 1.0f - 2.0f / (e + 1.0f);
}
__device__ __forceinline__ float softplus_f(float x){
    return (x > 20.0f) ? x : __logf(1.0f + __expf(x));
}

// lgkmcnt-only barrier: orders LDS ops, lets global loads stay in flight.
__device__ __forceinline__ void wg_barrier(){
    asm volatile("s_waitcnt lgkmcnt(0)\n\ts_barrier" ::: "memory");
}

// 6 waves:
//   waves 0-3: recurrence, 4-way K-split. Wave w owns z[32w..32w+32):
//     phase A: 8 LDS broadcasts of OWN z quarter + 16 pk-FMA -> partial -> pbuf.
//     ONE barrier/substep. combine: 4 conflict-free b32 reads -> h1sh (all waves
//     write identical values; own-write->own-read ordered by lgkm).
//     phase B: 2 lanes per z output, parity halves of the 50-dot, shfl_xor(1)
//     combine, even lane writes own z quarter. Last substep also writes zsnap.
//   waves 4-5: sigma / mu heads, LAGGED BY ONE STEP: at iteration t they emit
//     output t-1 from zsnap[(t-1)&1]. The write of zsnap[(t-1)&1] (between
//     barrier 10 of step t-1 and barrier 1 of step t) is ordered before the
//     read (after barrier 10 of step t) by the existing barriers — no race,
//     no extra in-loop barrier. One tail barrier publishes step T-1.
__global__ __launch_bounds__(384, 1)
void lode_kernel(const float* __restrict__ x, const float* __restrict__ dt,
                 const float* __restrict__ W1, const float* __restrict__ b1,
                 const float* __restrict__ W2, const float* __restrict__ b2,
                 const float* __restrict__ Wls1, const float* __restrict__ bls1,
                 const float* __restrict__ wls2, const float* __restrict__ bls2,
                 const float* __restrict__ Wlm1, const float* __restrict__ blm1,
                 float* __restrict__ out)
{
    __shared__ __align__(16) float zsh[HID];        // wave-private quarters
    __shared__ __align__(16) float zsnap[2][HID];   // per-step snapshot for heads
    __shared__ __align__(16) float pbuf[2][4][64];  // [dbuf][wave][lane] partials
    __shared__ __align__(16) float h1sh[64];        // h1 broadcast (50 real + 0s)

    const int tid = threadIdx.x;
    const int wid = tid >> 6;
    const int l   = tid & 63;

    if (wid < 4){
        // ================= recurrence waves =================
        const int base = wid << 5;              // z quarter start
        const int lc   = (l < MID) ? l : 0;

        // phase A weights: W1 rows [base, base+32), column lc -> 16 v2f
        v2f w1h[16];
        #pragma unroll
        for (int i = 0; i < 16; ++i){
            const float a = W1[(base + 2*i    )*MID + lc];
            const float b = W1[(base + 2*i + 1)*MID + lc];
            w1h[i] = (l < MID) ? mk2(a, b) : bc2(0.0f);
        }
        // x-part + bias: folded by wave 0 only
        float w1x[INP];
        #pragma unroll
        for (int j = 0; j < INP; ++j){
            const float v = W1[(HID + j)*MID + lc];
            w1x[j] = (wid == 0 && l < MID) ? v : 0.0f;
        }
        const float b1c = (wid == 0 && l < MID) ? b1[lc] : 0.0f;

        // phase B: output j = base + l/2; parity p sums k-halves [0,28)/[28,56)
        const int p  = l & 1;
        const int jc = base + (l >> 1);
        const int kb = p ? 28 : 0;
        v2f w2c[14];
        #pragma unroll
        for (int i = 0; i < 14; ++i){
            const int k0 = kb + 2*i, k1 = kb + 2*i + 1;
            const float a = (k0 < MID) ? W2[k0*HID + jc] : 0.0f;
            const float b = (k1 < MID) ? W2[k1*HID + jc] : 0.0f;
            w2c[i] = mk2(a, b);
        }
        const float b2c = b2[jc];

        float zj = 0.0f;
        if (p == 0) zsh[jc] = 0.0f;             // init own quarter

        // prefetch t=0 inputs
        float4 xa  = *reinterpret_cast<const float4*>(&x[0]);
        float4 xb  = *reinterpret_cast<const float4*>(&x[4]);
        float2 dtc = *reinterpret_cast<const float2*>(&dt[0]);

        for (int t = 0; t < T_STEPS; ++t){
            const int tn = (t + 1 < T_STEPS) ? t + 1 : t;
            const float4 xan = *reinterpret_cast<const float4*>(&x[tn*INP]);
            const float4 xbn = *reinterpret_cast<const float4*>(&x[tn*INP + 4]);
            const float2 dtn = *reinterpret_cast<const float2*>(&dt[2*tn]);

            float xacc = b1c;                    // nonzero on wave 0 only
            xacc = fmaf(xa.x, w1x[0], xacc); xacc = fmaf(xa.y, w1x[1], xacc);
            xacc = fmaf(xa.z, w1x[2], xacc); xacc = fmaf(xa.w, w1x[3], xacc);
            xacc = fmaf(xb.x, w1x[4], xacc); xacc = fmaf(xb.y, w1x[5], xacc);
            xacc = fmaf(xb.z, w1x[6], xacc); xacc = fmaf(xb.w, w1x[7], xacc);
            const float hstep = (dtc.y - dtc.x) * (1.0f / KSUB);

            #pragma unroll 2
            for (int s = 0; s < KSUB; ++s){
                // ---- phase A: partial over own z quarter ----
                v2f a0 = mk2(xacc, 0.0f), a1 = bc2(0.0f), a2 = bc2(0.0f), a3 = bc2(0.0f);
                #pragma unroll
                for (int m = 0; m < 2; ++m){
                    const float4 q0 = *reinterpret_cast<const float4*>(&zsh[base + 16*m +  0]);
                    const float4 q1 = *reinterpret_cast<const float4*>(&zsh[base + 16*m +  4]);
                    const float4 q2 = *reinterpret_cast<const float4*>(&zsh[base + 16*m +  8]);
                    const float4 q3 = *reinterpret_cast<const float4*>(&zsh[base + 16*m + 12]);
                    a0 = fma2(mk2(q0.x, q0.y), w1h[8*m+0], a0);
                    a1 = fma2(mk2(q0.z, q0.w), w1h[8*m+1], a1);
                    a2 = fma2(mk2(q1.x, q1.y), w1h[8*m+2], a2);
                    a3 = fma2(mk2(q1.z, q1.w), w1h[8*m+3], a3);
                    a0 = fma2(mk2(q2.x, q2.y), w1h[8*m+4], a0);
                    a1 = fma2(mk2(q2.z, q2.w), w1h[8*m+5], a1);
                    a2 = fma2(mk2(q3.x, q3.y), w1h[8*m+6], a2);
                    a3 = fma2(mk2(q3.z, q3.w), w1h[8*m+7], a3);
                }
                const v2f aa = (a0 + a1) + (a2 + a3);
                pbuf[s & 1][wid][l] = aa.x + aa.y;
                wg_barrier();                   // the substep's ONE barrier

                // ---- combine partials (conflict-free b32 reads) ----
                const float p0 = pbuf[s & 1][0][l];
                const float p1 = pbuf[s & 1][1][l];
                const float p2 = pbuf[s & 1][2][l];
                const float p3 = pbuf[s & 1][3][l];
                h1sh[l] = fast_tanh((p0 + p1) + (p2 + p3));  // lanes >= 50 -> 0

                // ---- phase B: half-dot per lane, shfl-combine ----
                v2f d0 = bc2(0.0f), d1 = bc2(0.0f), d2 = bc2(0.0f), d3 = bc2(0.0f);
                #pragma unroll
                for (int q = 0; q < 7; ++q){
                    const float4 hq = *reinterpret_cast<const float4*>(&h1sh[kb + 4*q]);
                    v2f* dsel0 = (q & 1) ? &d2 : &d0;
                    v2f* dsel1 = (q & 1) ? &d3 : &d1;
                    *dsel0 = fma2(mk2(hq.x, hq.y), w2c[2*q    ], *dsel0);
                    *dsel1 = fma2(mk2(hq.z, hq.w), w2c[2*q + 1], *dsel1);
                }
                const v2f dd = (d0 + d1) + (d2 + d3);
                float d = dd.x + dd.y;
                d += __shfl_xor(d, 1, 64);      // combine parity halves
                zj += hstep * fast_tanh(b2c + d);
                if (p == 0){
                    zsh[jc] = zj;               // own quarter
                    if (s == KSUB - 1) zsnap[t & 1][jc] = zj;
                }
            }

            xa = xan; xb = xbn; dtc = dtn;
        }
        wg_barrier();                           // tail: publish step T-1 snapshot
    } else {
        // ================= head waves (4 = sigma, 5 = mu), lag 1 step =================
        const float* __restrict__ Wh = (wid == 4) ? Wls1 : Wlm1;
        const float* __restrict__ bh = (wid == 4) ? bls1 : blm1;
        const v2f   bhp   = mk2(bh[2*l], bh[2*l+1]);
        const v2f   wls2p = mk2(wls2[2*l], wls2[2*l+1]);
        const float bls2s = bls2[0];

        for (int t = 0; t <= T_STEPS; ++t){
            if (t < T_STEPS){
                #pragma unroll 2
                for (int s = 0; s < KSUB; ++s) wg_barrier();   // match recurrence
            } else {
                wg_barrier();                   // matches recurrence tail barrier
            }
            if (t == 0) continue;
            const int ts = t - 1;               // emit output for step ts
            const float* zs = &zsnap[ts & 1][0];
            v2f pacc = bhp;
            #pragma unroll 4
            for (int k = 0; k < HID; k += 4){
                const float4 zv = *reinterpret_cast<const float4*>(&zs[k]);
                const v2f a0 = *reinterpret_cast<const v2f*>(&Wh[(k+0)*HID + 2*l]);
                const v2f a1 = *reinterpret_cast<const v2f*>(&Wh[(k+1)*HID + 2*l]);
                const v2f a2 = *reinterpret_cast<const v2f*>(&Wh[(k+2)*HID + 2*l]);
                const v2f a3 = *reinterpret_cast<const v2f*>(&Wh[(k+3)*HID + 2*l]);
                pacc = fma2(bc2(zv.x), a0, pacc);
                pacc = fma2(bc2(zv.y), a1, pacc);
                pacc = fma2(bc2(zv.z), a2, pacc);
                pacc = fma2(bc2(zv.w), a3, pacc);
            }
            pacc.x = fast_tanh(pacc.x); pacc.y = fast_tanh(pacc.y);
            float r = pacc.x*wls2p.x + pacc.y*wls2p.y;
            #pragma unroll
            for (int off = 1; off < 64; off <<= 1) r += __shfl_xor(r, off, 64);
            if (l == 0){
                if (wid == 4) out[T_STEPS + ts] = softplus_f(r + bls2s);  // sigma
                else          out[ts]           = r + bls2s;              // mu
            }
        }
    }
}

extern "C" void kernel_launch(void* const* d_in, const int* in_sizes, int n_in,
                              void* d_out, int out_size, void* d_ws, size_t ws_size,
                              hipStream_t stream)
{
    const float* x    = (const float*)d_in[0];
    const float* dt   = (const float*)d_in[1];
    const float* W1   = (const float*)d_in[2];
    const float* b1   = (const float*)d_in[3];
    const float* W2   = (const float*)d_in[4];
    const float* b2   = (const float*)d_in[5];
    const float* Wls1 = (const float*)d_in[6];
    const float* bls1 = (const float*)d_in[7];
    const float* wls2 = (const float*)d_in[8];
    const float* bls2 = (const float*)d_in[9];
    const float* Wlm1 = (const float*)d_in[10];
    const float* blm1 = (const float*)d_in[11];
    float* out = (float*)d_out;

    hipLaunchKernelGGL(lode_kernel, dim3(1), dim3(384), 0, stream,
                       x, dt, W1, b1, W2, b2, Wls1, bls1, wls2, bls2, Wlm1, blm1, out);
}

// Round 9
// 26129.324 us; speedup vs baseline: 2.3562x; 1.0519x over previous
//
#include <hip/hip_runtime.h>
#include <hip/hip_bf16.h>

#define T_STEPS 4096
#define HID 128
#define INP 8
#define MID 50
#define KSUB 10

__device__ __forceinline__ float rlane(float v, int i){
    // lane-uniform gather -> SGPR; usable directly as one FMA source operand
    return __int_as_float(__builtin_amdgcn_readlane(__float_as_int(v), i));
}

__device__ __forceinline__ float fast_tanh(float x){
    float e = __expf(2.0f * x);
    return 1.0f - 2.0f / (e + 1.0f);
}
__device__ __forceinline__ float softplus_f(float x){
    return (x > 20.0f) ? x : __logf(1.0f + __expf(x));
}

// lgkmcnt-only barrier: orders LDS ops, lets global loads stay in flight.
__device__ __forceinline__ void wg_barrier(){
    asm volatile("s_waitcnt lgkmcnt(0)\n\ts_barrier" ::: "memory");
}

// 6 waves. Recurrence is LDS-free except ONE partial-exchange per substep:
//   waves 0-3 (4-way K-split): wave w owns z[32w..32w+32), REGISTER-resident:
//     lane l holds z[32w + (l&31)] (replicated in lane pairs l, l+32; both
//     compute identical updates so no combine shuffle is needed).
//     phase A: own-quarter dot via 32 readlane + 32 FMA -> partial -> pbuf,
//     ONE barrier, 4 conflict-free b32 reads -> lane l holds h1[l] (register).
//     phase B: full 50-dot via 50 readlane + 50 FMA (pair-redundant), update z.
//   waves 4-5: sigma/mu heads, lagged one step, reading zsnap[(t-1)&1]
//     (ordering given by the existing 10 barriers/step; tail barrier for T-1).
__global__ __launch_bounds__(384, 2)
void lode_kernel(const float* __restrict__ x, const float* __restrict__ dt,
                 const float* __restrict__ W1, const float* __restrict__ b1,
                 const float* __restrict__ W2, const float* __restrict__ b2,
                 const float* __restrict__ Wls1, const float* __restrict__ bls1,
                 const float* __restrict__ wls2, const float* __restrict__ bls2,
                 const float* __restrict__ Wlm1, const float* __restrict__ blm1,
                 float* __restrict__ out)
{
    __shared__ __align__(16) float pbuf[2][4][64];  // [dbuf][wave][lane] partials
    __shared__ __align__(16) float zsnap[2][HID];   // per-step snapshot for heads

    const int tid = threadIdx.x;
    const int wid = tid >> 6;
    const int l   = tid & 63;

    if (wid < 4){
        // ================= recurrence waves =================
        const int base = wid << 5;              // z quarter start
        const int lc   = (l < MID) ? l : 0;     // clamped h1-output index

        // phase A weights: W1[base+i][lc], i = 0..31 (scalar, SGPR-z FMAs)
        float w1h[32];
        #pragma unroll
        for (int i = 0; i < 32; ++i){
            const float v = W1[(base + i)*MID + lc];
            w1h[i] = (l < MID) ? v : 0.0f;
        }
        // x-part + bias: folded into wave 0's partial only
        float w1x[INP];
        #pragma unroll
        for (int j = 0; j < INP; ++j){
            const float v = W1[(HID + j)*MID + lc];
            w1x[j] = (wid == 0 && l < MID) ? v : 0.0f;
        }
        const float b1c = (wid == 0 && l < MID) ? b1[lc] : 0.0f;

        // phase B weights: full column W2[k][jc], k = 0..49
        const int jc = base + (l & 31);
        float w2c[MID];
        #pragma unroll
        for (int k = 0; k < MID; ++k) w2c[k] = W2[k*HID + jc];
        const float b2c = b2[jc];

        float zj = 0.0f;                         // z[jc], replicated pair-wise

        // prefetch t=0 inputs
        float4 xa  = *reinterpret_cast<const float4*>(&x[0]);
        float4 xb  = *reinterpret_cast<const float4*>(&x[4]);
        float2 dtc = *reinterpret_cast<const float2*>(&dt[0]);

        for (int t = 0; t < T_STEPS; ++t){
            const int tn = (t + 1 < T_STEPS) ? t + 1 : t;
            const float4 xan = *reinterpret_cast<const float4*>(&x[tn*INP]);
            const float4 xbn = *reinterpret_cast<const float4*>(&x[tn*INP + 4]);
            const float2 dtn = *reinterpret_cast<const float2*>(&dt[2*tn]);

            float xacc = b1c;                    // nonzero on wave 0 only
            xacc = fmaf(xa.x, w1x[0], xacc); xacc = fmaf(xa.y, w1x[1], xacc);
            xacc = fmaf(xa.z, w1x[2], xacc); xacc = fmaf(xa.w, w1x[3], xacc);
            xacc = fmaf(xb.x, w1x[4], xacc); xacc = fmaf(xb.y, w1x[5], xacc);
            xacc = fmaf(xb.z, w1x[6], xacc); xacc = fmaf(xb.w, w1x[7], xacc);
            const float hstep = (dtc.y - dtc.x) * (1.0f / KSUB);

            #pragma unroll 2
            for (int s = 0; s < KSUB; ++s){
                // ---- phase A: partial over own z quarter (registers only) ----
                float a0 = xacc, a1 = 0.0f, a2 = 0.0f, a3 = 0.0f;
                #pragma unroll
                for (int i = 0; i < 32; i += 4){
                    a0 = fmaf(rlane(zj, i+0), w1h[i+0], a0);
                    a1 = fmaf(rlane(zj, i+1), w1h[i+1], a1);
                    a2 = fmaf(rlane(zj, i+2), w1h[i+2], a2);
                    a3 = fmaf(rlane(zj, i+3), w1h[i+3], a3);
                }
                pbuf[s & 1][wid][l] = (a0 + a1) + (a2 + a3);
                wg_barrier();                   // the substep's ONE barrier

                // ---- combine partials: lane l -> h1[l] in register ----
                const float p0 = pbuf[s & 1][0][l];
                const float p1 = pbuf[s & 1][1][l];
                const float p2 = pbuf[s & 1][2][l];
                const float p3 = pbuf[s & 1][3][l];
                const float h1v = fast_tanh((p0 + p1) + (p2 + p3)); // 0 for l>=50

                // ---- phase B: full 50-dot via readlane (pair-redundant) ----
                float d0 = 0.0f, d1 = 0.0f, d2 = 0.0f, d3 = 0.0f;
                #pragma unroll
                for (int k = 0; k < 48; k += 4){
                    d0 = fmaf(rlane(h1v, k+0), w2c[k+0], d0);
                    d1 = fmaf(rlane(h1v, k+1), w2c[k+1], d1);
                    d2 = fmaf(rlane(h1v, k+2), w2c[k+2], d2);
                    d3 = fmaf(rlane(h1v, k+3), w2c[k+3], d3);
                }
                d0 = fmaf(rlane(h1v, 48), w2c[48], d0);
                d1 = fmaf(rlane(h1v, 49), w2c[49], d1);
                const float d = (d0 + d1) + (d2 + d3);
                zj += hstep * fast_tanh(b2c + d);
            }

            if (l < 32) zsnap[t & 1][base + l] = zj;   // publish for heads

            xa = xan; xb = xbn; dtc = dtn;
        }
        wg_barrier();                           // tail: publish step T-1 snapshot
    } else {
        // ================= head waves (4 = sigma, 5 = mu), lag 1 step =================
        typedef float v2f __attribute__((ext_vector_type(2)));
        const float* __restrict__ Wh = (wid == 4) ? Wls1 : Wlm1;
        const float* __restrict__ bh = (wid == 4) ? bls1 : blm1;
        float2 bhp; bhp.x = bh[2*l]; bhp.y = bh[2*l+1];
        float2 wls2p; wls2p.x = wls2[2*l]; wls2p.y = wls2[2*l+1];
        const float bls2s = bls2[0];

        for (int t = 0; t <= T_STEPS; ++t){
            if (t < T_STEPS){
                #pragma unroll 2
                for (int s = 0; s < KSUB; ++s) wg_barrier();   // match recurrence
            } else {
                wg_barrier();                   // matches recurrence tail barrier
            }
            if (t == 0) continue;
            const int ts = t - 1;               // emit output for step ts
            const float* zs = &zsnap[ts & 1][0];
            float px = bhp.x, py = bhp.y;
            #pragma unroll 4
            for (int k = 0; k < HID; k += 4){
                const float4 zv = *reinterpret_cast<const float4*>(&zs[k]);
                const float2 a0 = *reinterpret_cast<const float2*>(&Wh[(k+0)*HID + 2*l]);
                const float2 a1 = *reinterpret_cast<const float2*>(&Wh[(k+1)*HID + 2*l]);
                const float2 a2 = *reinterpret_cast<const float2*>(&Wh[(k+2)*HID + 2*l]);
                const float2 a3 = *reinterpret_cast<const float2*>(&Wh[(k+3)*HID + 2*l]);
                px = fmaf(zv.x, a0.x, px); py = fmaf(zv.x, a0.y, py);
                px = fmaf(zv.y, a1.x, px); py = fmaf(zv.y, a1.y, py);
                px = fmaf(zv.z, a2.x, px); py = fmaf(zv.z, a2.y, py);
                px = fmaf(zv.w, a3.x, px); py = fmaf(zv.w, a3.y, py);
            }
            px = fast_tanh(px); py = fast_tanh(py);
            float r = px*wls2p.x + py*wls2p.y;
            #pragma unroll
            for (int off = 1; off < 64; off <<= 1) r += __shfl_xor(r, off, 64);
            if (l == 0){
                if (wid == 4) out[T_STEPS + ts] = softplus_f(r + bls2s);  // sigma
                else          out[ts]           = r + bls2s;              // mu
            }
        }
    }
}

extern "C" void kernel_launch(void* const* d_in, const int* in_sizes, int n_in,
                              void* d_out, int out_size, void* d_ws, size_t ws_size,
                              hipStream_t stream)
{
    const float* x    = (const float*)d_in[0];
    const float* dt   = (const float*)d_in[1];
    const float* W1   = (const float*)d_in[2];
    const float* b1   = (const float*)d_in[3];
    const float* W2   = (const float*)d_in[4];
    const float* b2   = (const float*)d_in[5];
    const float* Wls1 = (const float*)d_in[6];
    const float* bls1 = (const float*)d_in[7];
    const float* wls2 = (const float*)d_in[8];
    const float* bls2 = (const float*)d_in[9];
    const float* Wlm1 = (const float*)d_in[10];
    const float* blm1 = (const float*)d_in[11];
    float* out = (float*)d_out;

    hipLaunchKernelGGL(lode_kernel, dim3(1), dim3(384), 0, stream,
                       x, dt, W1, b1, W2, b2, Wls1, bls1, wls2, bls2, Wlm1, blm1, out);
}